// Round 10
// baseline (347.375 us; speedup 1.0000x reference)
//
#include <hip/hip_runtime.h>

// GCN 2-layer: h = relu(Ahat @ (x @ W) + b), twice.
// Round 18: fill2 deleted. k_aggGS (half-bucket) counting-sorts its own ebuf
// segment in LDS (R8 proved this hides under gather latency: 80.3 vs 81.8us),
// gathers hs1 with dinv[c] weights, burst-writes sorted cols to segmented
// col2 for layer 2, then gemm2 -> hs2. k_agg2 rebuilds sstart from a 64-lane
// shfl scan over deg (no row_ptr) and gathers from col2 at plain-agg speed.
// k_fusedA = bsort || gemm1 (both dependency-free); bsort's histogram pass
// also feeds global deg atomics; tiny k_dinv makes dinv.

#define NFEAT 128
#define BSH 7                  // 128 nodes per bucket
#define MAXNB 1024             // >= NB = ceil(N/128) = 782
#define BCAP 4096              // per-bucket ebuf capacity (mean 2046, sigma 45)
#define HP 72                  // ushorts per Bs row (64 k + 8 pad); word-stride 36 == 4 mod 32
#define YP 132                 // ushorts per yT row (128 + 4)
#define CH2 8192               // edges per bsort chunk (512 threads)
#define SEG 2048               // col2 ints per half-bucket segment

typedef __attribute__((ext_vector_type(8))) short s8v;  // 8 bf16 MFMA A/B frag
typedef __attribute__((ext_vector_type(4))) float f4v;  // MFMA C/D frag
typedef __attribute__((ext_vector_type(2))) float f2v;  // packed f32 pair

// ---- bf16 helpers (rne) ----
__device__ inline ushort f2bf(float f) {
    union { float f; uint u; } x; x.f = f;
    uint u = x.u;
    return (ushort)((u + 0x7fffu + ((u >> 16) & 1u)) >> 16);
}
__device__ inline f2v unpk(uint u) {
    union { uint u; float f; } lo, hi;
    lo.u = u << 16;
    hi.u = u & 0xffff0000u;
    return (f2v){lo.f, hi.f};
}
__device__ inline void upfma2(uint4 v, float g, f2v* a) {
    a[0] += g * unpk(v.x);
    a[1] += g * unpk(v.y);
    a[2] += g * unpk(v.z);
    a[3] += g * unpk(v.w);
}

// ---- per-node gather, explicit [s,e) index range (LDS or global col list) ----
// 4-deep pipelined 256B row gathers; weights dinv[c]; self-loop first.
__device__ inline void node_gather2(const uint4* __restrict__ hs4,
                                    const int* col, const float* __restrict__ dinv,
                                    int s, int e, int node, int sub, f2v* a) {
    uint4 vself = hs4[(size_t)node * 16 + sub];
    float dself = dinv[node];
    int nb = (e - s) >> 2;
    int k = s;
    if (nb > 0) {
        int c0 = col[k], c1 = col[k + 1], c2 = col[k + 2], c3 = col[k + 3];
        uint4 v0 = hs4[(size_t)c0 * 16 + sub];
        uint4 v1 = hs4[(size_t)c1 * 16 + sub];
        uint4 v2 = hs4[(size_t)c2 * 16 + sub];
        uint4 v3 = hs4[(size_t)c3 * 16 + sub];
        float g0 = dinv[c0], g1 = dinv[c1], g2 = dinv[c2], g3 = dinv[c3];
        int d0 = col[k + 4], d1 = col[k + 5], d2 = col[k + 6], d3 = col[k + 7];
        k += 8;
        upfma2(vself, dself, a);  // self-loop FIRST
        for (int it = 1; it < nb; ++it, k += 4) {
            uint4 w0 = hs4[(size_t)d0 * 16 + sub];
            uint4 w1 = hs4[(size_t)d1 * 16 + sub];
            uint4 w2 = hs4[(size_t)d2 * 16 + sub];
            uint4 w3 = hs4[(size_t)d3 * 16 + sub];
            float h0 = dinv[d0], h1 = dinv[d1], h2 = dinv[d2], h3 = dinv[d3];
            int t0 = col[k], t1 = col[k + 1], t2 = col[k + 2], t3 = col[k + 3];
            upfma2(v0, g0, a); upfma2(v1, g1, a); upfma2(v2, g2, a); upfma2(v3, g3, a);
            v0 = w0; v1 = w1; v2 = w2; v3 = w3;
            g0 = h0; g1 = h1; g2 = h2; g3 = h3;
            d0 = t0; d1 = t1; d2 = t2; d3 = t3;
        }
        upfma2(v0, g0, a); upfma2(v1, g1, a); upfma2(v2, g2, a); upfma2(v3, g3, a);
        k = s + nb * 4;
    } else {
        upfma2(vself, dself, a);
    }
    for (; k < e; ++k) {
        int c = col[k];
        upfma2(hs4[(size_t)c * 16 + sub], dinv[c], a);
    }
}

// ---- half-bucket counting sort: ebuf segment -> colL (LDS), cnt/sstart per node ----
__device__ inline void half_sort(const uint* __restrict__ ebuf,
                                 const int* __restrict__ gcnt,
                                 int b, int half, int* cnt, int* sstart, int* pre,
                                 int* colL) {
    int t = threadIdx.x;
    int m = min(gcnt[b], BCAP);
    const uint* eb = ebuf + (size_t)b * BCAP;
    if (t < 64) cnt[t] = 0;
    __syncthreads();
    for (int i = t; i < m; i += 256) {
        int low = (int)(eb[i] & 127u);
        if ((low >> 6) == half) atomicAdd(&cnt[low & 63], 1);
    }
    __syncthreads();
    if (t < 64) {
        int v = cnt[t];
        int sc = v;
#pragma unroll
        for (int off = 1; off < 64; off <<= 1) {
            int u = __shfl_up(sc, off, 64);
            if (t >= off) sc += u;
        }
        sstart[t] = sc - v;
        pre[t] = sc - v;
    }
    __syncthreads();
    for (int i = t; i < m; i += 256) {
        uint p = eb[i];
        int low = (int)(p & 127u);
        if ((low >> 6) == half) {
            int pos = atomicAdd(&pre[low & 63], 1);
            if (pos < SEG) colL[pos] = (int)(p >> BSH);
        }
    }
    __syncthreads();
}

// ---- stage one 64-k half of W into Bs[n][kk] bf16 (256-thread variant) ----
__device__ inline void stage_w_half(ushort* Bs, const float* __restrict__ W, int h, int t) {
#pragma unroll
    for (int i = 0; i < 8; i++) {
        int idx = t + i * 256;   // 0..2047
        int k4 = idx >> 7;
        int n = idx & 127;
        ushort o[4];
#pragma unroll
        for (int j = 0; j < 4; j++) o[j] = f2bf(W[(h * 64 + k4 * 4 + j) * NFEAT + n]);
        uint2 pk;
        __builtin_memcpy(&pk, o, 8);
        *(uint2*)&Bs[n * HP + k4 * 4] = pk;
    }
}

// ---- 512-thread variant ----
__device__ inline void stage_w_half512(ushort* Bs, const float* __restrict__ W, int h, int t) {
#pragma unroll
    for (int i = 0; i < 4; i++) {
        int idx = t + i * 512;   // 0..2047
        int k4 = idx >> 7;
        int n = idx & 127;
        ushort o[4];
#pragma unroll
        for (int j = 0; j < 4; j++) o[j] = f2bf(W[(h * 64 + k4 * 4 + j) * NFEAT + n]);
        uint2 pk;
        __builtin_memcpy(&pk, o, 8);
        *(uint2*)&Bs[n * HP + k4 * 4] = pk;
    }
}

// ---------------- bsort body (512 threads, 8192-edge chunks) + deg atomics ----
__device__ inline void bsort_body(char* smem, int sid,
                                  const int* __restrict__ src,
                                  const int* __restrict__ dst,
                                  int* __restrict__ gcnt,
                                  int* __restrict__ deg,
                                  uint* __restrict__ ebuf, int E, int NB) {
    int* cnt_ = (int*)smem;                 // 1024
    int* loff = cnt_ + MAXNB;               // 1024
    int* gbase = loff + MAXNB;              // 1024
    int* wpart = gbase + MAXNB;             // 8
    uint* sv = (uint*)(wpart + 8);          // 8192
    ushort* sb = (ushort*)(sv + CH2);       // 8192 ushort

    int t = threadIdx.x;
    int e0 = sid * CH2;
    int m = min(CH2, E - e0);

#pragma unroll
    for (int i = t; i < MAXNB; i += 512) cnt_[i] = 0;
    __syncthreads();
    for (int e = e0 + t; e < e0 + m; e += 512) {
        int d = dst[e];
        atomicAdd(&cnt_[d >> BSH], 1);
        atomicAdd(&deg[d], 1);   // global per-node degree (fire-and-forget)
    }
    __syncthreads();
    for (int b = t; b < NB; b += 512) {
        int c = cnt_[b];
        gbase[b] = c ? (b * BCAP + atomicAdd(&gcnt[b], c)) : 0;
    }
    int v0 = cnt_[t * 2], v1 = cnt_[t * 2 + 1];
    int my = v0 + v1;
    int lane = t & 63, wv = t >> 6;
    int sc = my;
#pragma unroll
    for (int off = 1; off < 64; off <<= 1) {
        int up = __shfl_up(sc, off, 64);
        if (lane >= off) sc += up;
    }
    if (lane == 63) wpart[wv] = sc;
    __syncthreads();
    int wbase = 0;
#pragma unroll
    for (int j = 0; j < 8; j++) wbase += (j < wv) ? wpart[j] : 0;
    int run = wbase + sc - my;
    loff[t * 2] = run; cnt_[t * 2] = run; run += v0;
    loff[t * 2 + 1] = run; cnt_[t * 2 + 1] = run;
    __syncthreads();
    for (int e = e0 + t; e < e0 + m; e += 512) {
        int d = dst[e];
        int b = d >> BSH;
        int p = atomicAdd(&cnt_[b], 1);
        sv[p] = ((uint)src[e] << BSH) | (uint)(d & ((1 << BSH) - 1));  // N < 2^17
        sb[p] = (ushort)b;
    }
    __syncthreads();
    for (int i = t; i < m; i += 512) {
        int b = sb[i];
        int slot = gbase[b] + (i - loff[b]);
        if (slot < (b + 1) * BCAP) ebuf[slot] = sv[i];
    }
}

// ---------------- gemm1 body (512 threads, 128 rows/block): hs = bf16(x@W1) ----
__device__ inline void gemm_body512(ushort* Bs, int gid, const float* __restrict__ x,
                                    const float* __restrict__ W,
                                    ushort* __restrict__ hs, int M) {
    int t = threadIdx.x;
    int w = t >> 6, l = t & 63;
    int q = l >> 4, ln = l & 15;
    int row0 = (gid * 8 + w) * 16;

    int arow = row0 + ln;
    if (arow >= M) arow = M - 1;
    s8v afr[4];
    const float* A = x + (size_t)arow * NFEAT + q * 8;
#pragma unroll
    for (int g = 0; g < 4; g++) {
        float4 f0 = *(const float4*)(A + g * 32);
        float4 f1 = *(const float4*)(A + g * 32 + 4);
        ushort o[8] = {f2bf(f0.x), f2bf(f0.y), f2bf(f0.z), f2bf(f0.w),
                       f2bf(f1.x), f2bf(f1.y), f2bf(f1.z), f2bf(f1.w)};
        __builtin_memcpy(&afr[g], o, 16);
    }

    f4v acc[8];
#pragma unroll
    for (int nt = 0; nt < 8; nt++) acc[nt] = (f4v){0.f, 0.f, 0.f, 0.f};

#pragma unroll
    for (int h = 0; h < 2; h++) {
        if (h) __syncthreads();
        stage_w_half512(Bs, W, h, t);
        __syncthreads();
#pragma unroll
        for (int nt = 0; nt < 8; nt++) {
            const ushort* Bp = Bs + (nt * 16 + ln) * HP + q * 8;
#pragma unroll
            for (int ks = 0; ks < 2; ks++) {
                s8v bfr = *(const s8v*)(Bp + ks * 32);
                acc[nt] = __builtin_amdgcn_mfma_f32_16x16x32_bf16(afr[h * 2 + ks], bfr, acc[nt], 0, 0, 0);
            }
        }
    }

#pragma unroll
    for (int r = 0; r < 4; r++) {
        int row = row0 + q * 4 + r;
        if (row < M) {
            ushort* hp = hs + (size_t)row * NFEAT + ln;
#pragma unroll
            for (int nt = 0; nt < 8; nt++) hp[nt * 16] = f2bf(acc[nt][r]);
        }
    }
}

// ---------------- fused: bsort+deg (1/5 of blocks) + gemm1 (4/5) ----------------
__global__ __launch_bounds__(512) void k_fusedA(const int* __restrict__ src,
                                                const int* __restrict__ dst,
                                                int* __restrict__ gcnt,
                                                int* __restrict__ deg,
                                                uint* __restrict__ ebuf,
                                                int E, int NB, int sortBlk,
                                                const float* __restrict__ x,
                                                const float* __restrict__ W1,
                                                ushort* __restrict__ hs, int M) {
    __shared__ __align__(16) char smem[61472];  // bsort 61472 | gemm Bs 18432
    int bid = blockIdx.x;
    int sid = bid / 5, r = bid % 5;
    if (r == 0 && sid < sortBlk) {
        bsort_body(smem, sid, src, dst, gcnt, deg, ebuf, E, NB);
    } else {
        int sorts_before = min((bid + 4) / 5, sortBlk);
        gemm_body512((ushort*)smem, bid - sorts_before, x, W1, hs, M);
    }
}

// ---------------- dinv = rsqrt(deg+1) ----------------
__global__ __launch_bounds__(256) void k_dinv(const int* __restrict__ deg,
                                              float* __restrict__ dinv, int N) {
    int i = blockIdx.x * 256 + threadIdx.x;
    if (i < N) dinv[i] = rsqrtf((float)(deg[i] + 1));
}

// ---------------- aggGS: half-bucket sort + col2 writeback + gather + gemm2 ----
__global__ __launch_bounds__(256, 4) void k_aggGS(const uint4* __restrict__ hs4,
                                                  const uint* __restrict__ ebuf,
                                                  const int* __restrict__ gcnt,
                                                  const float* __restrict__ dinv,
                                                  const float* __restrict__ bias,
                                                  const float* __restrict__ W2,
                                                  int* __restrict__ col2,
                                                  ushort* __restrict__ hs2, int N) {
    __shared__ __align__(16) char smem[36096];
    ushort* yT = (ushort*)smem;                 // 16896
    char* scr = smem + 16896;                   // 18432: colL then Bs
    int* cnt = (int*)(smem + 35328);            // 64
    int* sstart = (int*)(smem + 35584);         // 64
    int* pre = (int*)(smem + 35840);            // 64
    int* colL = (int*)scr;
    ushort* Bs = (ushort*)scr;

    int t = threadIdx.x;
    int hb = blockIdx.x;
    int b = hb >> 1, half = hb & 1;
    int base = (b << BSH) + half * 64;

    half_sort(ebuf, gcnt, b, half, cnt, sstart, pre, colL);

    // write the sorted segment out for layer 2 (coalesced; colL stays live)
    int m2 = min(sstart[63] + cnt[63], SEG);
    int* seg = col2 + (size_t)hb * SEG;
    for (int i = t; i < m2; i += 256) seg[i] = colL[i];

    int grp = t >> 4, sub = t & 15;
    const float4* b4 = (const float4*)bias;
    float4 bb0 = b4[sub * 2], bb1 = b4[sub * 2 + 1];

    // ---- phase A: gather + y = relu(dinv*acc + b1) -> yT
    for (int i = 0; i < 4; i++) {
        int lo = grp + i * 16;
        int node = base + lo;
        uint4 pk = make_uint4(0, 0, 0, 0);
        if (node < N) {
            f2v a[4];
#pragma unroll
            for (int j = 0; j < 4; j++) a[j] = (f2v){0.f, 0.f};
            int s = sstart[lo];
            int e = min(s + cnt[lo], SEG);
            node_gather2(hs4, colL, dinv, s, e, node, sub, a);
            float di = dinv[node];
            ushort o[8];
            o[0] = f2bf(fmaxf(fmaf(di, a[0].x, bb0.x), 0.f));
            o[1] = f2bf(fmaxf(fmaf(di, a[0].y, bb0.y), 0.f));
            o[2] = f2bf(fmaxf(fmaf(di, a[1].x, bb0.z), 0.f));
            o[3] = f2bf(fmaxf(fmaf(di, a[1].y, bb0.w), 0.f));
            o[4] = f2bf(fmaxf(fmaf(di, a[2].x, bb1.x), 0.f));
            o[5] = f2bf(fmaxf(fmaf(di, a[2].y, bb1.y), 0.f));
            o[6] = f2bf(fmaxf(fmaf(di, a[3].x, bb1.z), 0.f));
            o[7] = f2bf(fmaxf(fmaf(di, a[3].y, bb1.w), 0.f));
            __builtin_memcpy(&pk, o, 16);
        }
        *(uint4*)&yT[lo * YP + sub * 8] = pk;
    }
    __syncthreads();

    // ---- hoist A-frags, free scr for Bs
    int w = t >> 6, l = t & 63;
    int q = l >> 4, ln = l & 15;
    s8v a2[4];
#pragma unroll
    for (int g = 0; g < 4; g++)
        a2[g] = *(const s8v*)&yT[(w * 16 + ln) * YP + g * 32 + q * 8];
    __syncthreads();

    // ---- phase B: hs2 = yT @ W2 (unscaled bf16; agg2 applies dinv)
    f4v acc[8];
#pragma unroll
    for (int nt = 0; nt < 8; nt++) acc[nt] = (f4v){0.f, 0.f, 0.f, 0.f};
#pragma unroll
    for (int h = 0; h < 2; h++) {
        if (h) __syncthreads();
        stage_w_half(Bs, W2, h, t);
        __syncthreads();
#pragma unroll
        for (int nt = 0; nt < 8; nt++) {
            const ushort* Bp = Bs + (nt * 16 + ln) * HP + q * 8;
#pragma unroll
            for (int ks = 0; ks < 2; ks++) {
                s8v bfr = *(const s8v*)(Bp + ks * 32);
                acc[nt] = __builtin_amdgcn_mfma_f32_16x16x32_bf16(a2[h * 2 + ks], bfr, acc[nt], 0, 0, 0);
            }
        }
    }
#pragma unroll
    for (int rr = 0; rr < 4; rr++) {
        int node = base + w * 16 + q * 4 + rr;
        if (node < N) {
            ushort* hp = hs2 + (size_t)node * NFEAT + ln;
#pragma unroll
            for (int nt = 0; nt < 8; nt++) hp[nt * 16] = f2bf(acc[nt][rr]);
        }
    }
}

// ---------------- agg2: sstart from deg-scan + gather(col2) -> out (f32) --------
__global__ __launch_bounds__(256) void k_agg2(const uint4* __restrict__ hs4,
                                              const int* __restrict__ col2,
                                              const int* __restrict__ deg,
                                              const float* __restrict__ dinv,
                                              const float* __restrict__ bias,
                                              float* __restrict__ outp, int N) {
    __shared__ int sstart[64];
    __shared__ int scnt[64];
    int t = threadIdx.x;
    int hb = blockIdx.x;
    int base = ((hb >> 1) << BSH) + (hb & 1) * 64;

    if (t < 64) {
        int node = base + t;
        int d = (node < N) ? deg[node] : 0;
        int sc = d;
#pragma unroll
        for (int off = 1; off < 64; off <<= 1) {
            int u = __shfl_up(sc, off, 64);
            if (t >= off) sc += u;
        }
        sstart[t] = sc - d;
        scnt[t] = d;
    }
    __syncthreads();

    int grp = t >> 4, sub = t & 15;
    const int* seg = col2 + (size_t)hb * SEG;
    const float4* b4 = (const float4*)bias;
    float4 bb0 = b4[sub * 2], bb1 = b4[sub * 2 + 1];

    for (int i = 0; i < 4; i++) {
        int lo = grp + i * 16;
        int node = base + lo;
        if (node >= N) continue;  // no barriers below
        f2v a[4];
#pragma unroll
        for (int j = 0; j < 4; j++) a[j] = (f2v){0.f, 0.f};
        int s = min(sstart[lo], SEG);
        int e = min(sstart[lo] + scnt[lo], SEG);
        node_gather2(hs4, seg, dinv, s, e, node, sub, a);
        float di = dinv[node];
        float r[8];
        r[0] = fmaxf(fmaf(di, a[0].x, bb0.x), 0.f);
        r[1] = fmaxf(fmaf(di, a[0].y, bb0.y), 0.f);
        r[2] = fmaxf(fmaf(di, a[1].x, bb0.z), 0.f);
        r[3] = fmaxf(fmaf(di, a[1].y, bb0.w), 0.f);
        r[4] = fmaxf(fmaf(di, a[2].x, bb1.x), 0.f);
        r[5] = fmaxf(fmaf(di, a[2].y, bb1.y), 0.f);
        r[6] = fmaxf(fmaf(di, a[3].x, bb1.z), 0.f);
        r[7] = fmaxf(fmaf(di, a[3].y, bb1.w), 0.f);
        float* orow = outp + (size_t)node * NFEAT + sub * 8;
        f4v r0 = {r[0], r[1], r[2], r[3]};
        f4v r1 = {r[4], r[5], r[6], r[7]};
        __builtin_nontemporal_store(r0, (f4v*)orow);
        __builtin_nontemporal_store(r1, (f4v*)(orow + 4));
    }
}

// ---------------- launch ----------------
extern "C" void kernel_launch(void* const* d_in, const int* in_sizes, int n_in,
                              void* d_out, int out_size, void* d_ws, size_t ws_size,
                              hipStream_t stream) {
    const float* x = (const float*)d_in[0];
    const int* ei = (const int*)d_in[1];
    const float* W1 = (const float*)d_in[2];
    const float* b1 = (const float*)d_in[3];
    const float* W2 = (const float*)d_in[4];
    const float* b2 = (const float*)d_in[5];
    float* out = (float*)d_out;

    const int N = in_sizes[0] / NFEAT;  // 100000  (< 2^17 for 4B edge pack)
    const int E = in_sizes[1] / 2;      // 1600000
    const int* src = ei;
    const int* dst = ei + E;
    const int NB = (N + (1 << BSH) - 1) >> BSH;  // 782

    char* w = (char*)d_ws;
    size_t off = 0;
    auto alloc = [&](size_t bytes) -> void* {
        void* p = w + off;
        off = (off + bytes + 511) & ~(size_t)511;
        return p;
    };
    ushort* hs = (ushort*)alloc((size_t)N * NFEAT * 2);
    ushort* hs2 = (ushort*)alloc((size_t)N * NFEAT * 2);
    int* deg = (int*)alloc((size_t)N * 4);
    float* dinv = (float*)alloc((size_t)N * 4);
    uint* ebuf = (uint*)alloc((size_t)NB * BCAP * 4);        // 12.8 MB
    int* col2 = (int*)alloc(((size_t)2 * NB * SEG + 64) * 4);  // 12.8 MB + over-read pad
    int* gcnt = (int*)alloc((size_t)MAXNB * 4);
    (void)ws_size; (void)n_in; (void)out_size;

    const int sortBlk = (E + CH2 - 1) / CH2;      // 196 sort chunks (512 threads)
    const int gemmBlk = (N + 127) / 128;          // 782 gemm tiles (8 waves x 16 rows)
    const int aggBlk = 2 * NB;                    // 1564 half-bucket blocks

    hipMemsetAsync(deg, 0, (size_t)N * 4, stream);
    hipMemsetAsync(gcnt, 0, (size_t)MAXNB * 4, stream);
    // bsort+deg (1/5) || gemm1 (4/5) -- all inputs dependency-free
    k_fusedA<<<sortBlk + gemmBlk, 512, 0, stream>>>(src, dst, gcnt, deg, ebuf, E, NB,
                                                    sortBlk, x, W1, hs, N);
    k_dinv<<<(N + 255) / 256, 256, 0, stream>>>(deg, dinv, N);
    // half-bucket: sort + col2 writeback + gather(hs1) + gemm2 -> hs2
    k_aggGS<<<aggBlk, 256, 0, stream>>>((const uint4*)hs, ebuf, gcnt, dinv, b1, W2,
                                        col2, hs2, N);
    // final: deg-scan sstart + gather(hs2 via col2) -> out
    k_agg2<<<aggBlk, 256, 0, stream>>>((const uint4*)hs2, col2, deg, dinv, b2, out, N);
}

// Round 11
// 299.797 us; speedup vs baseline: 1.1587x; 1.1587x over previous
//
#include <hip/hip_runtime.h>

// GCN 2-layer: h = relu(Ahat @ (x @ W) + b), twice.
// Round 19: R9 structure (best: bsort@8192/512t -> fill2||gemm1 -> aggG ->
// agg2) with ONE change: k_aggG __launch_bounds__ (256,4) -> (256,6).
// R9 counters showed aggG occupancy pinned at 37% (= my own 4-blocks/CU cap)
// while LDS (18.4KB) allows 8; gather BW tracked occupancy (2.73 vs 3.85 TB/s
// at 65% occ for plain agg). 48 VGPR + 32 AGPR ~= 80 unified fits the
// 6-waves/EU bin (<=85). R10 lesson recorded: role-split fusion needs the
// union LDS footprint to keep >=4 blocks/CU (61.9KB bsort fusion -> 23% occ).

#define NFEAT 128
#define BSH 7                  // 128 nodes per bucket
#define MAXNB 1024             // >= NB = ceil(N/128) = 782
#define BCAP 4096              // per-bucket ebuf capacity (mean 2046, sigma 45)
#define HP 72                  // ushorts per Bs row (64 k + 8 pad); word-stride 36 == 4 mod 32
#define YP 132                 // ushorts per yT row (128 + 4)
#define CH2 8192               // edges per bsort chunk (512 threads)

typedef __attribute__((ext_vector_type(8))) short s8v;  // 8 bf16 MFMA A/B frag
typedef __attribute__((ext_vector_type(4))) float f4v;  // MFMA C/D frag
typedef __attribute__((ext_vector_type(2))) float f2v;  // packed f32 pair

// ---- bf16 helpers (rne) ----
__device__ inline ushort f2bf(float f) {
    union { float f; uint u; } x; x.f = f;
    uint u = x.u;
    return (ushort)((u + 0x7fffu + ((u >> 16) & 1u)) >> 16);
}
__device__ inline f2v unpk(uint u) {
    union { uint u; float f; } lo, hi;
    lo.u = u << 16;
    hi.u = u & 0xffff0000u;
    return (f2v){lo.f, hi.f};
}
__device__ inline void upfma2(uint4 v, float g, f2v* a) {
    a[0] += g * unpk(v.x);
    a[1] += g * unpk(v.y);
    a[2] += g * unpk(v.z);
    a[3] += g * unpk(v.w);
}

// ---- per-node gather: a[4] += dinv-weighted neighbor rows (4-deep pipeline) ----
__device__ inline void node_gather(const uint4* __restrict__ hs4,
                                   const int* __restrict__ row_ptr,
                                   const int* __restrict__ col,
                                   const float* __restrict__ dinv,
                                   int node, int sub, f2v* a) {
    uint4 vself = hs4[(size_t)node * 16 + sub];
    float dself = dinv[node];
    int s = row_ptr[node], e = row_ptr[node + 1];
    int nb = (e - s) >> 2;
    int k = s;
    if (nb > 0) {
        int c0 = col[k], c1 = col[k + 1], c2 = col[k + 2], c3 = col[k + 3];
        uint4 v0 = hs4[(size_t)c0 * 16 + sub];
        uint4 v1 = hs4[(size_t)c1 * 16 + sub];
        uint4 v2 = hs4[(size_t)c2 * 16 + sub];
        uint4 v3 = hs4[(size_t)c3 * 16 + sub];
        float g0 = dinv[c0], g1 = dinv[c1], g2 = dinv[c2], g3 = dinv[c3];
        int d0 = col[k + 4], d1 = col[k + 5], d2 = col[k + 6], d3 = col[k + 7];
        k += 8;
        upfma2(vself, dself, a);  // self-loop FIRST (order preserved)
        for (int it = 1; it < nb; ++it, k += 4) {
            uint4 w0 = hs4[(size_t)d0 * 16 + sub];
            uint4 w1 = hs4[(size_t)d1 * 16 + sub];
            uint4 w2 = hs4[(size_t)d2 * 16 + sub];
            uint4 w3 = hs4[(size_t)d3 * 16 + sub];
            float h0 = dinv[d0], h1 = dinv[d1], h2 = dinv[d2], h3 = dinv[d3];
            int t0 = col[k], t1 = col[k + 1], t2 = col[k + 2], t3 = col[k + 3];
            upfma2(v0, g0, a); upfma2(v1, g1, a); upfma2(v2, g2, a); upfma2(v3, g3, a);
            v0 = w0; v1 = w1; v2 = w2; v3 = w3;
            g0 = h0; g1 = h1; g2 = h2; g3 = h3;
            d0 = t0; d1 = t1; d2 = t2; d3 = t3;
        }
        upfma2(v0, g0, a); upfma2(v1, g1, a); upfma2(v2, g2, a); upfma2(v3, g3, a);
        k = s + nb * 4;
    } else {
        upfma2(vself, dself, a);
    }
    for (; k < e; ++k) {
        int c = col[k];
        upfma2(hs4[(size_t)c * 16 + sub], dinv[c], a);
    }
}

// ---- stage one 64-k half of W (f32 [k][n]) into Bs[n][kk] bf16 (256 threads) ----
__device__ inline void stage_w_half(ushort* Bs, const float* __restrict__ W, int h, int t) {
#pragma unroll
    for (int i = 0; i < 8; i++) {
        int idx = t + i * 256;   // 0..2047
        int k4 = idx >> 7;       // 0..15
        int n = idx & 127;
        ushort o[4];
#pragma unroll
        for (int j = 0; j < 4; j++) o[j] = f2bf(W[(h * 64 + k4 * 4 + j) * NFEAT + n]);
        uint2 pk;
        __builtin_memcpy(&pk, o, 8);
        *(uint2*)&Bs[n * HP + k4 * 4] = pk;
    }
}

// ---------------- bucket sort scatter: 512 threads, 8192-edge chunks ----------------
// Histogram over 128-node buckets -> ONE global reservation round per chunk ->
// shfl scan (2 buckets/thread, 8 wave partials) -> LDS scatter -> burst write.
__global__ __launch_bounds__(512) void k_bsort(const int* __restrict__ src,
                                               const int* __restrict__ dst,
                                               int* __restrict__ gcnt,
                                               uint* __restrict__ ebuf,
                                               int E, int NB) {
    __shared__ int cnt_[MAXNB];   // histogram -> running scatter counter
    __shared__ int loff[MAXNB];   // local exclusive offset per bucket
    __shared__ int gbase[MAXNB];  // global run base per bucket
    __shared__ int wpart[8];
    __shared__ uint sv[CH2];      // sorted packed edges (32 KB)
    __shared__ ushort sb[CH2];    // bucket id per sorted slot (16 KB)

    int t = threadIdx.x;
    int e0 = blockIdx.x * CH2;
    int m = min(CH2, E - e0);

#pragma unroll
    for (int i = t; i < MAXNB; i += 512) cnt_[i] = 0;
    __syncthreads();
    for (int e = e0 + t; e < e0 + m; e += 512) atomicAdd(&cnt_[dst[e] >> BSH], 1);
    __syncthreads();
    // reserve global runs (one atomic per nonzero bucket per chunk)
    for (int b = t; b < NB; b += 512) {
        int c = cnt_[b];
        gbase[b] = c ? (b * BCAP + atomicAdd(&gcnt[b], c)) : 0;
    }
    // exclusive scan over 1024 buckets: 2/thread + shfl wave scan + 8 partials
    int v0 = cnt_[t * 2], v1 = cnt_[t * 2 + 1];
    int my = v0 + v1;
    int lane = t & 63, wv = t >> 6;
    int sc = my;
#pragma unroll
    for (int off = 1; off < 64; off <<= 1) {
        int up = __shfl_up(sc, off, 64);
        if (lane >= off) sc += up;
    }
    if (lane == 63) wpart[wv] = sc;
    __syncthreads();  // wpart + gbase visible; all cnt_ reads done
    int wbase = 0;
#pragma unroll
    for (int j = 0; j < 8; j++) wbase += (j < wv) ? wpart[j] : 0;
    int run = wbase + sc - my;  // exclusive prefix over threads
    loff[t * 2] = run; cnt_[t * 2] = run; run += v0;
    loff[t * 2 + 1] = run; cnt_[t * 2 + 1] = run;
    __syncthreads();
    // LDS scatter to sorted order
    for (int e = e0 + t; e < e0 + m; e += 512) {
        int d = dst[e];
        int b = d >> BSH;
        int p = atomicAdd(&cnt_[b], 1);
        sv[p] = ((uint)src[e] << BSH) | (uint)(d & ((1 << BSH) - 1));  // N < 2^17
        sb[p] = (ushort)b;
    }
    __syncthreads();
    // burst write-out: consecutive i -> consecutive global within each run
    for (int i = t; i < m; i += 512) {
        int b = sb[i];
        int slot = gbase[b] + (i - loff[b]);
        if (slot < (b + 1) * BCAP) ebuf[slot] = sv[i];
    }
}

// ---------------- GEMM body: hs[m][n] = bf16( sum_k A[m][k] W[k][n] ) ----------
// 4 waves x 16 rows per block; W staged in two 64-k halves (18.4 KB LDS).
template <bool ABF16>
__device__ inline void gemm_body(ushort* Bs, int bid, const void* __restrict__ Ap,
                                 const float* __restrict__ W,
                                 ushort* __restrict__ hs, int M) {
    int t = threadIdx.x;
    int w = t >> 6, l = t & 63;
    int q = l >> 4, ln = l & 15;
    int row0 = (bid * 4 + w) * 16;

    int arow = row0 + ln;
    if (arow >= M) arow = M - 1;
    s8v afr[4];
    if (ABF16) {
        const ushort* A = (const ushort*)Ap + (size_t)arow * NFEAT + q * 8;
#pragma unroll
        for (int g = 0; g < 4; g++) afr[g] = *(const s8v*)(A + g * 32);
    } else {
        const float* A = (const float*)Ap + (size_t)arow * NFEAT + q * 8;
#pragma unroll
        for (int g = 0; g < 4; g++) {
            float4 f0 = *(const float4*)(A + g * 32);
            float4 f1 = *(const float4*)(A + g * 32 + 4);
            ushort o[8] = {f2bf(f0.x), f2bf(f0.y), f2bf(f0.z), f2bf(f0.w),
                           f2bf(f1.x), f2bf(f1.y), f2bf(f1.z), f2bf(f1.w)};
            __builtin_memcpy(&afr[g], o, 16);
        }
    }

    f4v acc[8];
#pragma unroll
    for (int nt = 0; nt < 8; nt++) acc[nt] = (f4v){0.f, 0.f, 0.f, 0.f};

#pragma unroll
    for (int h = 0; h < 2; h++) {
        if (h) __syncthreads();
        stage_w_half(Bs, W, h, t);
        __syncthreads();
#pragma unroll
        for (int nt = 0; nt < 8; nt++) {
            const ushort* Bp = Bs + (nt * 16 + ln) * HP + q * 8;
#pragma unroll
            for (int ks = 0; ks < 2; ks++) {
                s8v bfr = *(const s8v*)(Bp + ks * 32);
                acc[nt] = __builtin_amdgcn_mfma_f32_16x16x32_bf16(afr[h * 2 + ks], bfr, acc[nt], 0, 0, 0);
            }
        }
    }

#pragma unroll
    for (int r = 0; r < 4; r++) {
        int row = row0 + q * 4 + r;
        if (row < M) {
            ushort* hp = hs + (size_t)row * NFEAT + ln;
#pragma unroll
            for (int nt = 0; nt < 8; nt++) hp[nt * 16] = f2bf(acc[nt][r]);
        }
    }
}

// ---------------- fill2 body: per-bucket CSR finalize ----------------
__device__ inline void fill2_body(char* smem, int b,
                                  const uint* __restrict__ ebuf,
                                  const int* __restrict__ gcnt,
                                  int* __restrict__ row_ptr,
                                  float* __restrict__ dinv,
                                  int* __restrict__ col,
                                  int N, int E, int NB) {
    int* cnt = (int*)smem;            // 128
    int* pre = cnt + 128;             // 128
    int* sred = pre + 128;            // 256 (only 4 used)
    int* colL = sred + 256;           // 4096   total 4608 ints = 18432 B
    int t = threadIdx.x;
    int part = 0;
    for (int j = t; j < b; j += 256) part += gcnt[j];
#pragma unroll
    for (int off = 32; off >= 1; off >>= 1) part += __shfl_down(part, off, 64);
    if ((t & 63) == 0) sred[t >> 6] = part;
    __syncthreads();
    int gb = sred[0] + sred[1] + sred[2] + sred[3];
    int m = min(gcnt[b], BCAP);
    if (t < 128) cnt[t] = 0;
    __syncthreads();
    const uint* eb = ebuf + (size_t)b * BCAP;
    for (int i = t; i < m; i += 256) atomicAdd(&cnt[eb[i] & 127], 1);
    __syncthreads();
    if (t < 128) pre[t] = cnt[t];
    __syncthreads();
    for (int off = 1; off < 128; off <<= 1) {
        int add = (t >= off && t < 128) ? pre[t - off] : 0;
        __syncthreads();
        if (t < 128) pre[t] += add;
        __syncthreads();
    }
    if (t < 128) {
        pre[t] -= cnt[t];
        int node = (b << BSH) + t;
        if (node < N) {
            row_ptr[node] = gb + pre[t];
            dinv[node] = rsqrtf((float)(cnt[t] + 1));
        }
    }
    __syncthreads();
    for (int i = t; i < m; i += 256) {
        uint p = eb[i];
        int pos = atomicAdd(&pre[p & 127], 1);
        colL[pos] = (int)(p >> BSH);
    }
    __syncthreads();
    for (int i = t; i < m; i += 256) col[gb + i] = colL[i];  // coalesced
    if (b == NB - 1 && t == 0) row_ptr[N] = E;
}

// ---------------- fused: fill2 (1/3 of blocks) + gemm1 (2/3) ----------------
__global__ __launch_bounds__(256) void k_fused2(const uint* __restrict__ ebuf,
                                                const int* __restrict__ gcnt,
                                                int* __restrict__ row_ptr,
                                                float* __restrict__ dinv,
                                                int* __restrict__ col,
                                                int N, int E, int NB,
                                                const float* __restrict__ x,
                                                const float* __restrict__ W1,
                                                ushort* __restrict__ hs) {
    __shared__ __align__(16) char smem[18432];  // fill2 arrays OR gemm Bs
    int bid = blockIdx.x;
    int r = bid % 3;
    int fid = bid / 3;
    if (r == 0 && fid < NB) {
        fill2_body(smem, fid, ebuf, gcnt, row_ptr, dinv, col, N, E, NB);
    } else {
        int fills_before = min(fid + (r ? 1 : 0), NB);
        gemm_body<false>((ushort*)smem, bid - fills_before, x, W1, hs, N);
    }
}

// ---------------- fused aggregate(layer1) + gemm2, LDS reused yT->Bs ----------
__global__ __launch_bounds__(256, 6) void k_aggG(const uint4* __restrict__ hs4,
                                                 const int* __restrict__ row_ptr,
                                                 const int* __restrict__ col,
                                                 const float* __restrict__ dinv,
                                                 const float* __restrict__ bias,
                                                 const float* __restrict__ W2,
                                                 ushort* __restrict__ hs2, int N) {
    __shared__ __align__(16) ushort smem[128 * HP];  // 18432 B: yT (16896) then Bs
    ushort* yT = smem;
    ushort* Bs = smem;
    int t = threadIdx.x;
    int grp = t >> 4, sub = t & 15;
    int base = blockIdx.x * 64;

    const float4* b4 = (const float4*)bias;
    float4 bb0 = b4[sub * 2], bb1 = b4[sub * 2 + 1];

    // ---- phase A: gather + y = relu(dinv*acc + b), park in yT
    for (int i = 0; i < 4; i++) {
        int myn = grp + i * 16;
        int node = base + myn;
        uint4 pk = make_uint4(0, 0, 0, 0);
        if (node < N) {
            f2v a[4];
#pragma unroll
            for (int j = 0; j < 4; j++) a[j] = (f2v){0.f, 0.f};
            node_gather(hs4, row_ptr, col, dinv, node, sub, a);
            float di = dinv[node];
            ushort o[8];
            o[0] = f2bf(fmaxf(fmaf(di, a[0].x, bb0.x), 0.f));
            o[1] = f2bf(fmaxf(fmaf(di, a[0].y, bb0.y), 0.f));
            o[2] = f2bf(fmaxf(fmaf(di, a[1].x, bb0.z), 0.f));
            o[3] = f2bf(fmaxf(fmaf(di, a[1].y, bb0.w), 0.f));
            o[4] = f2bf(fmaxf(fmaf(di, a[2].x, bb1.x), 0.f));
            o[5] = f2bf(fmaxf(fmaf(di, a[2].y, bb1.y), 0.f));
            o[6] = f2bf(fmaxf(fmaf(di, a[3].x, bb1.z), 0.f));
            o[7] = f2bf(fmaxf(fmaf(di, a[3].y, bb1.w), 0.f));
            __builtin_memcpy(&pk, o, 16);
        }
        *(uint4*)&yT[myn * YP + sub * 8] = pk;
    }
    __syncthreads();

    // ---- hoist A-fragments to registers, then free yT for Bs
    int w = t >> 6, l = t & 63;
    int q = l >> 4, ln = l & 15;
    s8v a2[4];
#pragma unroll
    for (int g = 0; g < 4; g++)
        a2[g] = *(const s8v*)&yT[(w * 16 + ln) * YP + g * 32 + q * 8];
    __syncthreads();  // all reads of yT done before overwrite

    // ---- phase B: hs2[64 x 128] = yT @ W2 (Bs aliases yT storage)
    f4v acc[8];
#pragma unroll
    for (int nt = 0; nt < 8; nt++) acc[nt] = (f4v){0.f, 0.f, 0.f, 0.f};
#pragma unroll
    for (int h = 0; h < 2; h++) {
        if (h) __syncthreads();  // all waves done reading Bs half h-1
        stage_w_half(Bs, W2, h, t);
        __syncthreads();
#pragma unroll
        for (int nt = 0; nt < 8; nt++) {
            const ushort* Bp = Bs + (nt * 16 + ln) * HP + q * 8;
#pragma unroll
            for (int ks = 0; ks < 2; ks++) {
                s8v bfr = *(const s8v*)(Bp + ks * 32);
                acc[nt] = __builtin_amdgcn_mfma_f32_16x16x32_bf16(a2[h * 2 + ks], bfr, acc[nt], 0, 0, 0);
            }
        }
    }
    // ---- epilogue: store hs2 rows (col = nt*16 + ln, row = w*16 + q*4 + rr)
#pragma unroll
    for (int rr = 0; rr < 4; rr++) {
        int node = base + w * 16 + q * 4 + rr;
        if (node < N) {
            ushort* hp = hs2 + (size_t)node * NFEAT + ln;
#pragma unroll
            for (int nt = 0; nt < 8; nt++) hp[nt * 16] = f2bf(acc[nt][rr]);
        }
    }
}

// ---------------- Aggregation (layer 2, final): f32 output ----------------
__global__ __launch_bounds__(256) void k_aggregate(const uint4* __restrict__ hs4,
                                                   const int* __restrict__ row_ptr,
                                                   const int* __restrict__ col,
                                                   const float* __restrict__ dinv,
                                                   const float* __restrict__ bias,
                                                   float* __restrict__ outp, int N) {
    int node = blockIdx.x * 16 + (threadIdx.x >> 4);
    if (node >= N) return;
    int sub = threadIdx.x & 15;

    f2v a[4];
#pragma unroll
    for (int j = 0; j < 4; j++) a[j] = (f2v){0.f, 0.f};
    node_gather(hs4, row_ptr, col, dinv, node, sub, a);

    float di = dinv[node];
    const float4* b4 = (const float4*)bias;
    float4 b0 = b4[sub * 2], b1 = b4[sub * 2 + 1];
    float r[8];
    r[0] = fmaxf(fmaf(di, a[0].x, b0.x), 0.f);
    r[1] = fmaxf(fmaf(di, a[0].y, b0.y), 0.f);
    r[2] = fmaxf(fmaf(di, a[1].x, b0.z), 0.f);
    r[3] = fmaxf(fmaf(di, a[1].y, b0.w), 0.f);
    r[4] = fmaxf(fmaf(di, a[2].x, b1.x), 0.f);
    r[5] = fmaxf(fmaf(di, a[2].y, b1.y), 0.f);
    r[6] = fmaxf(fmaf(di, a[3].x, b1.z), 0.f);
    r[7] = fmaxf(fmaf(di, a[3].y, b1.w), 0.f);
    float* orow = outp + (size_t)node * NFEAT + sub * 8;
    f4v r0 = {r[0], r[1], r[2], r[3]};
    f4v r1 = {r[4], r[5], r[6], r[7]};
    __builtin_nontemporal_store(r0, (f4v*)orow);
    __builtin_nontemporal_store(r1, (f4v*)(orow + 4));
}

// ---------------- launch ----------------
extern "C" void kernel_launch(void* const* d_in, const int* in_sizes, int n_in,
                              void* d_out, int out_size, void* d_ws, size_t ws_size,
                              hipStream_t stream) {
    const float* x = (const float*)d_in[0];
    const int* ei = (const int*)d_in[1];
    const float* W1 = (const float*)d_in[2];
    const float* b1 = (const float*)d_in[3];
    const float* W2 = (const float*)d_in[4];
    const float* b2 = (const float*)d_in[5];
    float* out = (float*)d_out;

    const int N = in_sizes[0] / NFEAT;  // 100000  (< 2^17 for 4B edge pack)
    const int E = in_sizes[1] / 2;      // 1600000
    const int* src = ei;
    const int* dst = ei + E;
    const int NB = (N + (1 << BSH) - 1) >> BSH;  // 782

    char* w = (char*)d_ws;
    size_t off = 0;
    auto alloc = [&](size_t bytes) -> void* {
        void* p = w + off;
        off = (off + bytes + 511) & ~(size_t)511;
        return p;
    };
    ushort* hs = (ushort*)alloc((size_t)N * NFEAT * 2);
    ushort* hs2 = (ushort*)alloc((size_t)N * NFEAT * 2);
    int* row_ptr = (int*)alloc((size_t)(N + 1) * 4);
    float* dinv = (float*)alloc((size_t)N * 4);
    int* col = (int*)alloc((size_t)(E + 64) * 4);   // +64: gather prefetch over-read pad
    uint* ebuf = (uint*)alloc((size_t)NB * BCAP * 4);  // 12.8 MB
    int* gcnt = (int*)alloc((size_t)MAXNB * 4);
    (void)ws_size; (void)n_in; (void)out_size;

    const int sortBlk = (E + CH2 - 1) / CH2;      // 196 sort chunks (512 threads)
    const int gemmBlk = (N + 63) / 64;            // 1563 gemm/aggG tiles
    const int aggBlk = (N + 15) / 16;             // 16 nodes per block

    hipMemsetAsync(gcnt, 0, (size_t)MAXNB * 4, stream);
    k_bsort<<<sortBlk, 512, 0, stream>>>(src, dst, gcnt, ebuf, E, NB);
    // fill2 (1/3) || gemm1 (2/3)
    k_fused2<<<NB + gemmBlk, 256, 0, stream>>>(ebuf, gcnt, row_ptr, dinv, col, N, E, NB,
                                               x, W1, hs);
    // fused aggregate(layer1) + gemm2 -> hs2 ; then final aggregate -> out
    k_aggG<<<gemmBlk, 256, 0, stream>>>((const uint4*)hs, row_ptr, col, dinv, b1, W2, hs2, N);
    k_aggregate<<<aggBlk, 256, 0, stream>>>((const uint4*)hs2, row_ptr, col, dinv, b2, out, N);
}

// Round 12
// 294.184 us; speedup vs baseline: 1.1808x; 1.0191x over previous
//
#include <hip/hip_runtime.h>

// GCN 2-layer: h = relu(Ahat @ (x @ W) + b), twice.
// Round 20: revert R11's (256,6) experiment -> back to R9 exact config (best
// measured: 293.6us). R11 evidence: 6-waves/EU bin leaves ~53 VGPR after the
// 32-AGPR accumulator; the 4-deep gather pipeline needs ~56 -> scratch spill
// (FETCH +22MB, WRITE +9MB), aggG 81.8->90.7. (256,4) keeps the pipeline in
// registers; 4 blocks/CU is the max for this kernel. Structure: bsort@8192/512t
// -> fill2||gemm1 (18.4KB union LDS) -> aggG(gather+gemm2, lb(256,4)) -> agg2.

#define NFEAT 128
#define BSH 7                  // 128 nodes per bucket
#define MAXNB 1024             // >= NB = ceil(N/128) = 782
#define BCAP 4096              // per-bucket ebuf capacity (mean 2046, sigma 45)
#define HP 72                  // ushorts per Bs row (64 k + 8 pad); word-stride 36 == 4 mod 32
#define YP 132                 // ushorts per yT row (128 + 4)
#define CH2 8192               // edges per bsort chunk (512 threads)

typedef __attribute__((ext_vector_type(8))) short s8v;  // 8 bf16 MFMA A/B frag
typedef __attribute__((ext_vector_type(4))) float f4v;  // MFMA C/D frag
typedef __attribute__((ext_vector_type(2))) float f2v;  // packed f32 pair

// ---- bf16 helpers (rne) ----
__device__ inline ushort f2bf(float f) {
    union { float f; uint u; } x; x.f = f;
    uint u = x.u;
    return (ushort)((u + 0x7fffu + ((u >> 16) & 1u)) >> 16);
}
__device__ inline f2v unpk(uint u) {
    union { uint u; float f; } lo, hi;
    lo.u = u << 16;
    hi.u = u & 0xffff0000u;
    return (f2v){lo.f, hi.f};
}
__device__ inline void upfma2(uint4 v, float g, f2v* a) {
    a[0] += g * unpk(v.x);
    a[1] += g * unpk(v.y);
    a[2] += g * unpk(v.z);
    a[3] += g * unpk(v.w);
}

// ---- per-node gather: a[4] += dinv-weighted neighbor rows (4-deep pipeline) ----
__device__ inline void node_gather(const uint4* __restrict__ hs4,
                                   const int* __restrict__ row_ptr,
                                   const int* __restrict__ col,
                                   const float* __restrict__ dinv,
                                   int node, int sub, f2v* a) {
    uint4 vself = hs4[(size_t)node * 16 + sub];
    float dself = dinv[node];
    int s = row_ptr[node], e = row_ptr[node + 1];
    int nb = (e - s) >> 2;
    int k = s;
    if (nb > 0) {
        int c0 = col[k], c1 = col[k + 1], c2 = col[k + 2], c3 = col[k + 3];
        uint4 v0 = hs4[(size_t)c0 * 16 + sub];
        uint4 v1 = hs4[(size_t)c1 * 16 + sub];
        uint4 v2 = hs4[(size_t)c2 * 16 + sub];
        uint4 v3 = hs4[(size_t)c3 * 16 + sub];
        float g0 = dinv[c0], g1 = dinv[c1], g2 = dinv[c2], g3 = dinv[c3];
        int d0 = col[k + 4], d1 = col[k + 5], d2 = col[k + 6], d3 = col[k + 7];
        k += 8;
        upfma2(vself, dself, a);  // self-loop FIRST (order preserved)
        for (int it = 1; it < nb; ++it, k += 4) {
            uint4 w0 = hs4[(size_t)d0 * 16 + sub];
            uint4 w1 = hs4[(size_t)d1 * 16 + sub];
            uint4 w2 = hs4[(size_t)d2 * 16 + sub];
            uint4 w3 = hs4[(size_t)d3 * 16 + sub];
            float h0 = dinv[d0], h1 = dinv[d1], h2 = dinv[d2], h3 = dinv[d3];
            int t0 = col[k], t1 = col[k + 1], t2 = col[k + 2], t3 = col[k + 3];
            upfma2(v0, g0, a); upfma2(v1, g1, a); upfma2(v2, g2, a); upfma2(v3, g3, a);
            v0 = w0; v1 = w1; v2 = w2; v3 = w3;
            g0 = h0; g1 = h1; g2 = h2; g3 = h3;
            d0 = t0; d1 = t1; d2 = t2; d3 = t3;
        }
        upfma2(v0, g0, a); upfma2(v1, g1, a); upfma2(v2, g2, a); upfma2(v3, g3, a);
        k = s + nb * 4;
    } else {
        upfma2(vself, dself, a);
    }
    for (; k < e; ++k) {
        int c = col[k];
        upfma2(hs4[(size_t)c * 16 + sub], dinv[c], a);
    }
}

// ---- stage one 64-k half of W (f32 [k][n]) into Bs[n][kk] bf16 (256 threads) ----
__device__ inline void stage_w_half(ushort* Bs, const float* __restrict__ W, int h, int t) {
#pragma unroll
    for (int i = 0; i < 8; i++) {
        int idx = t + i * 256;   // 0..2047
        int k4 = idx >> 7;       // 0..15
        int n = idx & 127;
        ushort o[4];
#pragma unroll
        for (int j = 0; j < 4; j++) o[j] = f2bf(W[(h * 64 + k4 * 4 + j) * NFEAT + n]);
        uint2 pk;
        __builtin_memcpy(&pk, o, 8);
        *(uint2*)&Bs[n * HP + k4 * 4] = pk;
    }
}

// ---------------- bucket sort scatter: 512 threads, 8192-edge chunks ----------------
// Histogram over 128-node buckets -> ONE global reservation round per chunk ->
// shfl scan (2 buckets/thread, 8 wave partials) -> LDS scatter -> burst write.
__global__ __launch_bounds__(512) void k_bsort(const int* __restrict__ src,
                                               const int* __restrict__ dst,
                                               int* __restrict__ gcnt,
                                               uint* __restrict__ ebuf,
                                               int E, int NB) {
    __shared__ int cnt_[MAXNB];   // histogram -> running scatter counter
    __shared__ int loff[MAXNB];   // local exclusive offset per bucket
    __shared__ int gbase[MAXNB];  // global run base per bucket
    __shared__ int wpart[8];
    __shared__ uint sv[CH2];      // sorted packed edges (32 KB)
    __shared__ ushort sb[CH2];    // bucket id per sorted slot (16 KB)

    int t = threadIdx.x;
    int e0 = blockIdx.x * CH2;
    int m = min(CH2, E - e0);

#pragma unroll
    for (int i = t; i < MAXNB; i += 512) cnt_[i] = 0;
    __syncthreads();
    for (int e = e0 + t; e < e0 + m; e += 512) atomicAdd(&cnt_[dst[e] >> BSH], 1);
    __syncthreads();
    // reserve global runs (one atomic per nonzero bucket per chunk)
    for (int b = t; b < NB; b += 512) {
        int c = cnt_[b];
        gbase[b] = c ? (b * BCAP + atomicAdd(&gcnt[b], c)) : 0;
    }
    // exclusive scan over 1024 buckets: 2/thread + shfl wave scan + 8 partials
    int v0 = cnt_[t * 2], v1 = cnt_[t * 2 + 1];
    int my = v0 + v1;
    int lane = t & 63, wv = t >> 6;
    int sc = my;
#pragma unroll
    for (int off = 1; off < 64; off <<= 1) {
        int up = __shfl_up(sc, off, 64);
        if (lane >= off) sc += up;
    }
    if (lane == 63) wpart[wv] = sc;
    __syncthreads();  // wpart + gbase visible; all cnt_ reads done
    int wbase = 0;
#pragma unroll
    for (int j = 0; j < 8; j++) wbase += (j < wv) ? wpart[j] : 0;
    int run = wbase + sc - my;  // exclusive prefix over threads
    loff[t * 2] = run; cnt_[t * 2] = run; run += v0;
    loff[t * 2 + 1] = run; cnt_[t * 2 + 1] = run;
    __syncthreads();
    // LDS scatter to sorted order
    for (int e = e0 + t; e < e0 + m; e += 512) {
        int d = dst[e];
        int b = d >> BSH;
        int p = atomicAdd(&cnt_[b], 1);
        sv[p] = ((uint)src[e] << BSH) | (uint)(d & ((1 << BSH) - 1));  // N < 2^17
        sb[p] = (ushort)b;
    }
    __syncthreads();
    // burst write-out: consecutive i -> consecutive global within each run
    for (int i = t; i < m; i += 512) {
        int b = sb[i];
        int slot = gbase[b] + (i - loff[b]);
        if (slot < (b + 1) * BCAP) ebuf[slot] = sv[i];
    }
}

// ---------------- GEMM body: hs[m][n] = bf16( sum_k A[m][k] W[k][n] ) ----------
// 4 waves x 16 rows per block; W staged in two 64-k halves (18.4 KB LDS).
template <bool ABF16>
__device__ inline void gemm_body(ushort* Bs, int bid, const void* __restrict__ Ap,
                                 const float* __restrict__ W,
                                 ushort* __restrict__ hs, int M) {
    int t = threadIdx.x;
    int w = t >> 6, l = t & 63;
    int q = l >> 4, ln = l & 15;
    int row0 = (bid * 4 + w) * 16;

    int arow = row0 + ln;
    if (arow >= M) arow = M - 1;
    s8v afr[4];
    if (ABF16) {
        const ushort* A = (const ushort*)Ap + (size_t)arow * NFEAT + q * 8;
#pragma unroll
        for (int g = 0; g < 4; g++) afr[g] = *(const s8v*)(A + g * 32);
    } else {
        const float* A = (const float*)Ap + (size_t)arow * NFEAT + q * 8;
#pragma unroll
        for (int g = 0; g < 4; g++) {
            float4 f0 = *(const float4*)(A + g * 32);
            float4 f1 = *(const float4*)(A + g * 32 + 4);
            ushort o[8] = {f2bf(f0.x), f2bf(f0.y), f2bf(f0.z), f2bf(f0.w),
                           f2bf(f1.x), f2bf(f1.y), f2bf(f1.z), f2bf(f1.w)};
            __builtin_memcpy(&afr[g], o, 16);
        }
    }

    f4v acc[8];
#pragma unroll
    for (int nt = 0; nt < 8; nt++) acc[nt] = (f4v){0.f, 0.f, 0.f, 0.f};

#pragma unroll
    for (int h = 0; h < 2; h++) {
        if (h) __syncthreads();
        stage_w_half(Bs, W, h, t);
        __syncthreads();
#pragma unroll
        for (int nt = 0; nt < 8; nt++) {
            const ushort* Bp = Bs + (nt * 16 + ln) * HP + q * 8;
#pragma unroll
            for (int ks = 0; ks < 2; ks++) {
                s8v bfr = *(const s8v*)(Bp + ks * 32);
                acc[nt] = __builtin_amdgcn_mfma_f32_16x16x32_bf16(afr[h * 2 + ks], bfr, acc[nt], 0, 0, 0);
            }
        }
    }

#pragma unroll
    for (int r = 0; r < 4; r++) {
        int row = row0 + q * 4 + r;
        if (row < M) {
            ushort* hp = hs + (size_t)row * NFEAT + ln;
#pragma unroll
            for (int nt = 0; nt < 8; nt++) hp[nt * 16] = f2bf(acc[nt][r]);
        }
    }
}

// ---------------- fill2 body: per-bucket CSR finalize ----------------
__device__ inline void fill2_body(char* smem, int b,
                                  const uint* __restrict__ ebuf,
                                  const int* __restrict__ gcnt,
                                  int* __restrict__ row_ptr,
                                  float* __restrict__ dinv,
                                  int* __restrict__ col,
                                  int N, int E, int NB) {
    int* cnt = (int*)smem;            // 128
    int* pre = cnt + 128;             // 128
    int* sred = pre + 128;            // 256 (only 4 used)
    int* colL = sred + 256;           // 4096   total 4608 ints = 18432 B
    int t = threadIdx.x;
    int part = 0;
    for (int j = t; j < b; j += 256) part += gcnt[j];
#pragma unroll
    for (int off = 32; off >= 1; off >>= 1) part += __shfl_down(part, off, 64);
    if ((t & 63) == 0) sred[t >> 6] = part;
    __syncthreads();
    int gb = sred[0] + sred[1] + sred[2] + sred[3];
    int m = min(gcnt[b], BCAP);
    if (t < 128) cnt[t] = 0;
    __syncthreads();
    const uint* eb = ebuf + (size_t)b * BCAP;
    for (int i = t; i < m; i += 256) atomicAdd(&cnt[eb[i] & 127], 1);
    __syncthreads();
    if (t < 128) pre[t] = cnt[t];
    __syncthreads();
    for (int off = 1; off < 128; off <<= 1) {
        int add = (t >= off && t < 128) ? pre[t - off] : 0;
        __syncthreads();
        if (t < 128) pre[t] += add;
        __syncthreads();
    }
    if (t < 128) {
        pre[t] -= cnt[t];
        int node = (b << BSH) + t;
        if (node < N) {
            row_ptr[node] = gb + pre[t];
            dinv[node] = rsqrtf((float)(cnt[t] + 1));
        }
    }
    __syncthreads();
    for (int i = t; i < m; i += 256) {
        uint p = eb[i];
        int pos = atomicAdd(&pre[p & 127], 1);
        colL[pos] = (int)(p >> BSH);
    }
    __syncthreads();
    for (int i = t; i < m; i += 256) col[gb + i] = colL[i];  // coalesced
    if (b == NB - 1 && t == 0) row_ptr[N] = E;
}

// ---------------- fused: fill2 (1/3 of blocks) + gemm1 (2/3) ----------------
__global__ __launch_bounds__(256) void k_fused2(const uint* __restrict__ ebuf,
                                                const int* __restrict__ gcnt,
                                                int* __restrict__ row_ptr,
                                                float* __restrict__ dinv,
                                                int* __restrict__ col,
                                                int N, int E, int NB,
                                                const float* __restrict__ x,
                                                const float* __restrict__ W1,
                                                ushort* __restrict__ hs) {
    __shared__ __align__(16) char smem[18432];  // fill2 arrays OR gemm Bs
    int bid = blockIdx.x;
    int r = bid % 3;
    int fid = bid / 3;
    if (r == 0 && fid < NB) {
        fill2_body(smem, fid, ebuf, gcnt, row_ptr, dinv, col, N, E, NB);
    } else {
        int fills_before = min(fid + (r ? 1 : 0), NB);
        gemm_body<false>((ushort*)smem, bid - fills_before, x, W1, hs, N);
    }
}

// ---------------- fused aggregate(layer1) + gemm2, LDS reused yT->Bs ----------
__global__ __launch_bounds__(256, 4) void k_aggG(const uint4* __restrict__ hs4,
                                                 const int* __restrict__ row_ptr,
                                                 const int* __restrict__ col,
                                                 const float* __restrict__ dinv,
                                                 const float* __restrict__ bias,
                                                 const float* __restrict__ W2,
                                                 ushort* __restrict__ hs2, int N) {
    __shared__ __align__(16) ushort smem[128 * HP];  // 18432 B: yT (16896) then Bs
    ushort* yT = smem;
    ushort* Bs = smem;
    int t = threadIdx.x;
    int grp = t >> 4, sub = t & 15;
    int base = blockIdx.x * 64;

    const float4* b4 = (const float4*)bias;
    float4 bb0 = b4[sub * 2], bb1 = b4[sub * 2 + 1];

    // ---- phase A: gather + y = relu(dinv*acc + b), park in yT
    for (int i = 0; i < 4; i++) {
        int myn = grp + i * 16;
        int node = base + myn;
        uint4 pk = make_uint4(0, 0, 0, 0);
        if (node < N) {
            f2v a[4];
#pragma unroll
            for (int j = 0; j < 4; j++) a[j] = (f2v){0.f, 0.f};
            node_gather(hs4, row_ptr, col, dinv, node, sub, a);
            float di = dinv[node];
            ushort o[8];
            o[0] = f2bf(fmaxf(fmaf(di, a[0].x, bb0.x), 0.f));
            o[1] = f2bf(fmaxf(fmaf(di, a[0].y, bb0.y), 0.f));
            o[2] = f2bf(fmaxf(fmaf(di, a[1].x, bb0.z), 0.f));
            o[3] = f2bf(fmaxf(fmaf(di, a[1].y, bb0.w), 0.f));
            o[4] = f2bf(fmaxf(fmaf(di, a[2].x, bb1.x), 0.f));
            o[5] = f2bf(fmaxf(fmaf(di, a[2].y, bb1.y), 0.f));
            o[6] = f2bf(fmaxf(fmaf(di, a[3].x, bb1.z), 0.f));
            o[7] = f2bf(fmaxf(fmaf(di, a[3].y, bb1.w), 0.f));
            __builtin_memcpy(&pk, o, 16);
        }
        *(uint4*)&yT[myn * YP + sub * 8] = pk;
    }
    __syncthreads();

    // ---- hoist A-fragments to registers, then free yT for Bs
    int w = t >> 6, l = t & 63;
    int q = l >> 4, ln = l & 15;
    s8v a2[4];
#pragma unroll
    for (int g = 0; g < 4; g++)
        a2[g] = *(const s8v*)&yT[(w * 16 + ln) * YP + g * 32 + q * 8];
    __syncthreads();  // all reads of yT done before overwrite

    // ---- phase B: hs2[64 x 128] = yT @ W2 (Bs aliases yT storage)
    f4v acc[8];
#pragma unroll
    for (int nt = 0; nt < 8; nt++) acc[nt] = (f4v){0.f, 0.f, 0.f, 0.f};
#pragma unroll
    for (int h = 0; h < 2; h++) {
        if (h) __syncthreads();  // all waves done reading Bs half h-1
        stage_w_half(Bs, W2, h, t);
        __syncthreads();
#pragma unroll
        for (int nt = 0; nt < 8; nt++) {
            const ushort* Bp = Bs + (nt * 16 + ln) * HP + q * 8;
#pragma unroll
            for (int ks = 0; ks < 2; ks++) {
                s8v bfr = *(const s8v*)(Bp + ks * 32);
                acc[nt] = __builtin_amdgcn_mfma_f32_16x16x32_bf16(a2[h * 2 + ks], bfr, acc[nt], 0, 0, 0);
            }
        }
    }
    // ---- epilogue: store hs2 rows (col = nt*16 + ln, row = w*16 + q*4 + rr)
#pragma unroll
    for (int rr = 0; rr < 4; rr++) {
        int node = base + w * 16 + q * 4 + rr;
        if (node < N) {
            ushort* hp = hs2 + (size_t)node * NFEAT + ln;
#pragma unroll
            for (int nt = 0; nt < 8; nt++) hp[nt * 16] = f2bf(acc[nt][rr]);
        }
    }
}

// ---------------- Aggregation (layer 2, final): f32 output ----------------
__global__ __launch_bounds__(256) void k_aggregate(const uint4* __restrict__ hs4,
                                                   const int* __restrict__ row_ptr,
                                                   const int* __restrict__ col,
                                                   const float* __restrict__ dinv,
                                                   const float* __restrict__ bias,
                                                   float* __restrict__ outp, int N) {
    int node = blockIdx.x * 16 + (threadIdx.x >> 4);
    if (node >= N) return;
    int sub = threadIdx.x & 15;

    f2v a[4];
#pragma unroll
    for (int j = 0; j < 4; j++) a[j] = (f2v){0.f, 0.f};
    node_gather(hs4, row_ptr, col, dinv, node, sub, a);

    float di = dinv[node];
    const float4* b4 = (const float4*)bias;
    float4 b0 = b4[sub * 2], b1 = b4[sub * 2 + 1];
    float r[8];
    r[0] = fmaxf(fmaf(di, a[0].x, b0.x), 0.f);
    r[1] = fmaxf(fmaf(di, a[0].y, b0.y), 0.f);
    r[2] = fmaxf(fmaf(di, a[1].x, b0.z), 0.f);
    r[3] = fmaxf(fmaf(di, a[1].y, b0.w), 0.f);
    r[4] = fmaxf(fmaf(di, a[2].x, b1.x), 0.f);
    r[5] = fmaxf(fmaf(di, a[2].y, b1.y), 0.f);
    r[6] = fmaxf(fmaf(di, a[3].x, b1.z), 0.f);
    r[7] = fmaxf(fmaf(di, a[3].y, b1.w), 0.f);
    float* orow = outp + (size_t)node * NFEAT + sub * 8;
    f4v r0 = {r[0], r[1], r[2], r[3]};
    f4v r1 = {r[4], r[5], r[6], r[7]};
    __builtin_nontemporal_store(r0, (f4v*)orow);
    __builtin_nontemporal_store(r1, (f4v*)(orow + 4));
}

// ---------------- launch ----------------
extern "C" void kernel_launch(void* const* d_in, const int* in_sizes, int n_in,
                              void* d_out, int out_size, void* d_ws, size_t ws_size,
                              hipStream_t stream) {
    const float* x = (const float*)d_in[0];
    const int* ei = (const int*)d_in[1];
    const float* W1 = (const float*)d_in[2];
    const float* b1 = (const float*)d_in[3];
    const float* W2 = (const float*)d_in[4];
    const float* b2 = (const float*)d_in[5];
    float* out = (float*)d_out;

    const int N = in_sizes[0] / NFEAT;  // 100000  (< 2^17 for 4B edge pack)
    const int E = in_sizes[1] / 2;      // 1600000
    const int* src = ei;
    const int* dst = ei + E;
    const int NB = (N + (1 << BSH) - 1) >> BSH;  // 782

    char* w = (char*)d_ws;
    size_t off = 0;
    auto alloc = [&](size_t bytes) -> void* {
        void* p = w + off;
        off = (off + bytes + 511) & ~(size_t)511;
        return p;
    };
    ushort* hs = (ushort*)alloc((size_t)N * NFEAT * 2);
    ushort* hs2 = (ushort*)alloc((size_t)N * NFEAT * 2);
    int* row_ptr = (int*)alloc((size_t)(N + 1) * 4);
    float* dinv = (float*)alloc((size_t)N * 4);
    int* col = (int*)alloc((size_t)(E + 64) * 4);   // +64: gather prefetch over-read pad
    uint* ebuf = (uint*)alloc((size_t)NB * BCAP * 4);  // 12.8 MB
    int* gcnt = (int*)alloc((size_t)MAXNB * 4);
    (void)ws_size; (void)n_in; (void)out_size;

    const int sortBlk = (E + CH2 - 1) / CH2;      // 196 sort chunks (512 threads)
    const int gemmBlk = (N + 63) / 64;            // 1563 gemm/aggG tiles
    const int aggBlk = (N + 15) / 16;             // 16 nodes per block

    hipMemsetAsync(gcnt, 0, (size_t)MAXNB * 4, stream);
    k_bsort<<<sortBlk, 512, 0, stream>>>(src, dst, gcnt, ebuf, E, NB);
    // fill2 (1/3) || gemm1 (2/3)
    k_fused2<<<NB + gemmBlk, 256, 0, stream>>>(ebuf, gcnt, row_ptr, dinv, col, N, E, NB,
                                               x, W1, hs);
    // fused aggregate(layer1) + gemm2 -> hs2 ; then final aggregate -> out
    k_aggG<<<gemmBlk, 256, 0, stream>>>((const uint4*)hs, row_ptr, col, dinv, b1, W2, hs2, N);
    k_aggregate<<<aggBlk, 256, 0, stream>>>((const uint4*)hs2, row_ptr, col, dinv, b2, out, N);
}